// Round 1
// baseline (261.228 us; speedup 1.0000x reference)
//
#include <hip/hip_runtime.h>

#define DIM 2048

// XOR-swizzle LDS addresses: bits 2..4 ^= bits 7..9. Keeps 16B chunks
// contiguous (only touches bits >=2) and makes every transpose phase
// bank-uniform (8 dwords/bank, conflict-free).
__device__ __forceinline__ int sw(int e) {
  return e ^ (((e >> 7) & 7) << 2);
}

// Exact sign flip: signs are +/-1 int32; -1 has the int sign bit set.
__device__ __forceinline__ float4 sign_flip(float4 v, uint4 s) {
  float4 r;
  r.x = __uint_as_float(__float_as_uint(v.x) ^ (s.x & 0x80000000u));
  r.y = __uint_as_float(__float_as_uint(v.y) ^ (s.y & 0x80000000u));
  r.z = __uint_as_float(__float_as_uint(v.z) ^ (s.z & 0x80000000u));
  r.w = __uint_as_float(__float_as_uint(v.w) ^ (s.w & 0x80000000u));
  return r;
}

#define BFLY(a, b) { float _t = (a); (a) = _t + (b); (b) = _t - (b); }

__device__ __forceinline__ void bf4_pair(float4 &a, float4 &b) {
  BFLY(a.x, b.x); BFLY(a.y, b.y); BFLY(a.z, b.z); BFLY(a.w, b.w);
}

// Butterfly element-index bits 0 and 1 (within the float4 components).
__device__ __forceinline__ void bf_comps(float4 &a) {
  BFLY(a.x, a.y); BFLY(a.z, a.w);   // bit 0
  BFLY(a.x, a.z); BFLY(a.y, a.w);   // bit 1
}

// Butterfly the 3 bits of the 8-register index (strides 1,2,4).
__device__ __forceinline__ void bf_oct(float4 v[8]) {
  bf4_pair(v[0], v[1]); bf4_pair(v[2], v[3]);
  bf4_pair(v[4], v[5]); bf4_pair(v[6], v[7]);
  bf4_pair(v[0], v[2]); bf4_pair(v[1], v[3]);
  bf4_pair(v[4], v[6]); bf4_pair(v[5], v[7]);
  bf4_pair(v[0], v[4]); bf4_pair(v[1], v[5]);
  bf4_pair(v[2], v[6]); bf4_pair(v[3], v[7]);
}

// Cross-lane butterfly on lane bit 0 / 1 via DPP quad_perm (VALU rate,
// no DS-pipe traffic). 0xB1 = [1,0,3,2] (xor1), 0x4E = [2,3,0,1] (xor2).
template <int CTRL>
__device__ __forceinline__ float dpp_mov(float x) {
  return __int_as_float(
      __builtin_amdgcn_mov_dpp(__float_as_int(x), CTRL, 0xF, 0xF, true));
}

template <int CTRL>
__device__ __forceinline__ void dpp_stage(float4 v[8], float sgn) {
  #pragma unroll
  for (int i = 0; i < 8; ++i) {
    float px = dpp_mov<CTRL>(v[i].x);
    float py = dpp_mov<CTRL>(v[i].y);
    float pz = dpp_mov<CTRL>(v[i].z);
    float pw = dpp_mov<CTRL>(v[i].w);
    // lane with bit clear: x + partner ; lane with bit set: partner - x
    v[i].x = fmaf(sgn, v[i].x, px);
    v[i].y = fmaf(sgn, v[i].y, py);
    v[i].z = fmaf(sgn, v[i].z, pz);
    v[i].w = fmaf(sgn, v[i].w, pw);
  }
}

// Wave-local LDS ordering: the LDS slice is per-wave private, so a full
// workgroup barrier is never needed. DS ops from one wave are processed
// in order by the DS pipe; this fence drains outstanding LDS ops and the
// "memory" clobber stops the compiler from moving LDS accesses across it.
__device__ __forceinline__ void lds_fence() {
  asm volatile("s_waitcnt lgkmcnt(0)" ::: "memory");
}

// One wave per TWO 2048-float rows (time-sharing one 8 KiB LDS slice).
// 32 floats/lane/row in registers.
// Layout1 (load):  e = c*256 + lane*4 + r        (comps=bits0-1, c=bits8-10, lane=bits2-7)
// Layout2 (after transpose 1): e = r + 4*l1 + 8*l2 + 16*j + 128*l0 + 256*(lane>>3)
// Layout3 (after transpose 2): e = r + 4*l1 + 8*l0 + 16*l2 + 32*l3 + 64*l4 + 128*l5 + 256*c
__global__ __launch_bounds__(256, 4) void srht2_kernel(
    const float* __restrict__ x, const int* __restrict__ signs,
    float* __restrict__ out, int nrows) {
  __shared__ __align__(16) float lds[4][DIM];
  const int lane = threadIdx.x & 63;
  const int wv   = threadIdx.x >> 6;
  const int row0 = (blockIdx.x * 4 + wv) * 2;

  const float sgn1 = (lane & 1) ? -1.0f : 1.0f;
  const float sgn2 = (lane & 2) ? -1.0f : 1.0f;

  const float4* __restrict__ xr0 = (const float4*)(x + (size_t)row0 * DIM);
  const float4* __restrict__ xr1 = xr0 + DIM / 4;
  const uint4*  __restrict__ s0  = (const uint4*)signs;

  float4 a[8], b[8];
  #pragma unroll
  for (int c = 0; c < 8; ++c) {
    a[c] = xr0[c * 64 + lane];
    b[c] = xr1[c * 64 + lane];
  }
  #pragma unroll
  for (int c = 0; c < 8; ++c) {
    const uint4 s = s0[c * 64 + lane];      // shared by both rows
    a[c] = sign_flip(a[c], s);
    b[c] = sign_flip(b[c], s);
  }

  // ---- pass 1, pre-transpose: bits 0,1 (comps), 8,9,10 (c), 2,3 (DPP) ----
  #pragma unroll
  for (int c = 0; c < 8; ++c) { bf_comps(a[c]); bf_comps(b[c]); }
  bf_oct(a); bf_oct(b);
  dpp_stage<0xB1>(a, sgn1); dpp_stage<0xB1>(b, sgn1);   // bit 2
  dpp_stage<0x4E>(a, sgn2); dpp_stage<0x4E>(b, sgn2);   // bit 3

  // ---- transpose 1 (per-wave LDS slice, swizzled, b128 both ways) ----
  float* L = lds[wv];
  const int rbase = (((lane >> 1) & 1) << 2) | (((lane >> 2) & 1) << 3)
                  | ((lane & 1) << 7) | ((lane >> 3) << 8);

  float4 wa[8], wb[8];
  #pragma unroll
  for (int c = 0; c < 8; ++c)
    *(float4*)(L + sw(c * 256 + lane * 4)) = a[c];
  lds_fence();
  #pragma unroll
  for (int j = 0; j < 8; ++j)
    wa[j] = *(const float4*)(L + sw(rbase + (j << 4)));
  lds_fence();
  #pragma unroll
  for (int c = 0; c < 8; ++c)
    *(float4*)(L + sw(c * 256 + lane * 4)) = b[c];
  lds_fence();
  #pragma unroll
  for (int j = 0; j < 8; ++j)
    wb[j] = *(const float4*)(L + sw(rbase + (j << 4)));

  // ---- pass 1, post-transpose: bits 4,5,6 (j), 7 (DPP) ----
  bf_oct(wa); bf_oct(wb);
  dpp_stage<0xB1>(wa, sgn1); dpp_stage<0xB1>(wb, sgn1);   // bit 7

  // ---- pass 2: sign flip (layout2 addressing into signs[1]) ----
  const uint4* __restrict__ s1 = (const uint4*)(signs + DIM);
  #pragma unroll
  for (int j = 0; j < 8; ++j) {
    const uint4 s = s1[(rbase >> 2) + (j << 2)];  // shared by both rows
    wa[j] = sign_flip(wa[j], s);
    wb[j] = sign_flip(wb[j], s);
  }

  // ---- pass 2, pre-transpose: bits 0,1 (comps), 4,5,6 (j), 7,2 (DPP) ----
  #pragma unroll
  for (int j = 0; j < 8; ++j) { bf_comps(wa[j]); bf_comps(wb[j]); }
  bf_oct(wa); bf_oct(wb);
  dpp_stage<0xB1>(wa, sgn1); dpp_stage<0xB1>(wb, sgn1);   // bit 7
  dpp_stage<0x4E>(wa, sgn2); dpp_stage<0x4E>(wb, sgn2);   // bit 2

  // ---- transpose 2 ----
  const int rb2 = ((lane & 1) << 3) | (((lane >> 1) & 1) << 2)
                | (((lane >> 2) & 1) << 4) | (((lane >> 3) & 1) << 5)
                | (((lane >> 4) & 1) << 6) | (((lane >> 5) & 1) << 7);

  lds_fence();   // wb reads fully drained before slice reuse
  #pragma unroll
  for (int j = 0; j < 8; ++j)
    *(float4*)(L + sw(rbase + (j << 4))) = wa[j];
  lds_fence();
  #pragma unroll
  for (int c = 0; c < 8; ++c)
    a[c] = *(const float4*)(L + sw(rb2 + (c << 8)));
  lds_fence();
  #pragma unroll
  for (int j = 0; j < 8; ++j)
    *(float4*)(L + sw(rbase + (j << 4))) = wb[j];
  lds_fence();
  #pragma unroll
  for (int c = 0; c < 8; ++c)
    b[c] = *(const float4*)(L + sw(rb2 + (c << 8)));

  // ---- pass 2, post-transpose: bits 8,9,10 (c), 3 (DPP) ----
  bf_oct(a); bf_oct(b);
  dpp_stage<0xB1>(a, sgn1); dpp_stage<0xB1>(b, sgn1);   // bit 3

  // ---- scale (exact pow2) and coalesced store ----
  const float sc = 1.0f / 2048.0f;
  float4* __restrict__ orow0 = (float4*)(out + (size_t)row0 * DIM);
  float4* __restrict__ orow1 = orow0 + DIM / 4;
  #pragma unroll
  for (int c = 0; c < 8; ++c) {
    float4 ta = a[c];
    ta.x *= sc; ta.y *= sc; ta.z *= sc; ta.w *= sc;
    orow0[(rb2 >> 2) + (c << 6)] = ta;
    float4 tb = b[c];
    tb.x *= sc; tb.y *= sc; tb.z *= sc; tb.w *= sc;
    orow1[(rb2 >> 2) + (c << 6)] = tb;
  }
}

extern "C" void kernel_launch(void* const* d_in, const int* in_sizes, int n_in,
                              void* d_out, int out_size, void* d_ws, size_t ws_size,
                              hipStream_t stream) {
  const float* x     = (const float*)d_in[0];
  const int*   signs = (const int*)d_in[1];
  float*       out   = (float*)d_out;
  const int nrows   = in_sizes[0] / DIM;   // 16384
  const int nblocks = nrows / 8;           // 4 waves/block, 2 rows/wave
  hipLaunchKernelGGL(srht2_kernel, dim3(nblocks), dim3(256), 0, stream,
                     x, signs, out, nrows);
}